// Round 1
// baseline (22772.369 us; speedup 1.0000x reference)
//
#include <hip/hip_runtime.h>
#include <hip/hip_bf16.h>

typedef __bf16 bf16_t;
typedef bf16_t bf16x8 __attribute__((ext_vector_type(8)));
typedef float f32x4 __attribute__((ext_vector_type(4)));

#define T_SEQ 512
#define NB 128
#define HID 1024
#define FIN 64
#define LD0 1088   // 64 + 1024
#define LD1 2048   // 1024 + 1024
#define HB (NB * HID)  // 131072 elements of h/c state per layer

__device__ __forceinline__ float sigm_f(float x) { return 1.0f / (1.0f + __expf(-x)); }
__device__ __forceinline__ float tanh_f(float x) { return 2.0f * sigm_f(2.0f * x) - 1.0f; }

// One-shot prep: bf16-cast weights into concatenated [W_ih | W_hh] layouts,
// bf16-cast x, combine biases, zero states, init out with b_fc.
__global__ __launch_bounds__(256) void prep_kernel(
    const float* __restrict__ x,
    const float* __restrict__ Wih0, const float* __restrict__ Whh0,
    const float* __restrict__ bih0, const float* __restrict__ bhh0,
    const float* __restrict__ Wih1, const float* __restrict__ Whh1,
    const float* __restrict__ bih1, const float* __restrict__ bhh1,
    const float* __restrict__ bfc,
    bf16_t* __restrict__ Wcat0, bf16_t* __restrict__ Wcat1,
    bf16_t* __restrict__ xbf,
    float* __restrict__ bias0, float* __restrict__ bias1,
    bf16_t* __restrict__ hs0, bf16_t* __restrict__ hs1,
    float* __restrict__ c0, float* __restrict__ c1,
    float* __restrict__ out)
{
    const unsigned stride = gridDim.x * blockDim.x;
    const unsigned i0 = blockIdx.x * blockDim.x + threadIdx.x;

    for (unsigned i = i0; i < 4096u * LD1; i += stride) {
        unsigned m = i >> 11, kk = i & 2047u;
        float v = (kk < HID) ? Wih1[m * HID + kk] : Whh1[m * HID + (kk - HID)];
        Wcat1[i] = (bf16_t)v;
    }
    for (unsigned i = i0; i < 4096u * LD0; i += stride) {
        unsigned m = i / LD0, kk = i - m * LD0;
        float v = (kk < FIN) ? Wih0[m * FIN + kk] : Whh0[m * HID + (kk - FIN)];
        Wcat0[i] = (bf16_t)v;
    }
    for (unsigned i = i0; i < (unsigned)(NB * T_SEQ * FIN); i += stride)
        xbf[i] = (bf16_t)x[i];
    for (unsigned i = i0; i < (unsigned)(NB * T_SEQ * 64); i += stride)
        out[i] = bfc[i & 63u];  // FC accumulates atomically on top of b_fc
    for (unsigned i = i0; i < 2u * HB; i += stride) {
        hs0[i] = (bf16_t)0.0f; hs1[i] = (bf16_t)0.0f;
    }
    for (unsigned i = i0; i < (unsigned)HB; i += stride) { c0[i] = 0.0f; c1[i] = 0.0f; }
    for (unsigned i = i0; i < 4096u; i += stride) {
        bias0[i] = bih0[i] + bhh0[i];
        bias1[i] = bih1[i] + bhh1[i];
    }
}

// Pipeline step k: blocks 0..255 do layer0 @ t=k, blocks 256..511 do layer1 @ t=k-1.
// Per layer: 64 hidden-tiles(16) x 4 batch-tiles(32). Block = 4 waves, wave w = gate w.
// g[m][b] = sum_k Wcat[m][k] * B[k][b], B rows are batch rows (K-contiguous) so both
// MFMA fragments are direct 16B global loads (A: W row-major, B: x/h batch-major).
__global__ __launch_bounds__(256) void lstm_step_kernel(
    int k,
    const bf16_t* __restrict__ Wcat0, const float* __restrict__ bias0,
    const bf16_t* __restrict__ xbf,
    bf16_t* __restrict__ hs0, float* __restrict__ c0,
    bf16_t* __restrict__ h1buf,
    const bf16_t* __restrict__ Wcat1, const float* __restrict__ bias1,
    bf16_t* __restrict__ hs1, float* __restrict__ c1,
    const float* __restrict__ Wfc,
    float* __restrict__ out)
{
    const int layer = blockIdx.x >> 8;
    const int t = (layer == 0) ? k : (k - 1);
    if (t < 0 || t >= T_SEQ) return;

    const int bx = blockIdx.x & 255;
    const int ht = bx >> 2;        // hidden tile 0..63
    const int bt = bx & 3;         // batch tile 0..3
    const int j0 = ht * 16;
    const int n0 = bt * 32;
    const int tid = threadIdx.x;
    const int w = tid >> 6;        // gate: 0=i 1=f 2=g 3=o
    const int lane = tid & 63;
    const int q = lane >> 4;
    const int l = lane & 15;

    __shared__ float lds_g[4 * 16 * 33];  // activated gates [gate][hid][batch], pad 33
    __shared__ float lds_h[16 * 33];      // layer1: fp32 h for fused FC

    f32x4 acc0 = {0.f, 0.f, 0.f, 0.f};
    f32x4 acc1 = {0.f, 0.f, 0.f, 0.f};

    const int bA = n0 + l;         // batch row, B-frag 0
    const int bB = n0 + 16 + l;    // batch row, B-frag 1

    // Double-buffered h state: buffer (t&1) holds state entering step t.
    const bf16_t* hr; bf16_t* hw; float* cc; const float* bias;
    if (layer == 0) {
        hr = hs0 + (size_t)(t & 1) * HB; hw = hs0 + (size_t)((t + 1) & 1) * HB;
        cc = c0; bias = bias0;
    } else {
        hr = hs1 + (size_t)(t & 1) * HB; hw = hs1 + (size_t)((t + 1) & 1) * HB;
        cc = c1; bias = bias1;
    }

    if (layer == 0) {
        const bf16_t* arow = Wcat0 + (size_t)(w * HID + j0 + l) * LD0 + q * 8;
        const bf16_t* xA = xbf + ((size_t)bA * T_SEQ + t) * FIN + q * 8;
        const bf16_t* xB = xbf + ((size_t)bB * T_SEQ + t) * FIN + q * 8;
#pragma unroll
        for (int p = 0; p < 2; ++p) {  // K panels from x_t (K=64)
            bf16x8 a  = *(const bf16x8*)(arow + p * 32);
            bf16x8 b0 = *(const bf16x8*)(xA + p * 32);
            bf16x8 b1 = *(const bf16x8*)(xB + p * 32);
            acc0 = __builtin_amdgcn_mfma_f32_16x16x32_bf16(a, b0, acc0, 0, 0, 0);
            acc1 = __builtin_amdgcn_mfma_f32_16x16x32_bf16(a, b1, acc1, 0, 0, 0);
        }
        const bf16_t* hA = hr + (size_t)bA * HID + q * 8;
        const bf16_t* hB = hr + (size_t)bB * HID + q * 8;
#pragma unroll 4
        for (int p = 0; p < 32; ++p) { // K panels from h (K=1024)
            bf16x8 a  = *(const bf16x8*)(arow + FIN + p * 32);
            bf16x8 b0 = *(const bf16x8*)(hA + p * 32);
            bf16x8 b1 = *(const bf16x8*)(hB + p * 32);
            acc0 = __builtin_amdgcn_mfma_f32_16x16x32_bf16(a, b0, acc0, 0, 0, 0);
            acc1 = __builtin_amdgcn_mfma_f32_16x16x32_bf16(a, b1, acc1, 0, 0, 0);
        }
    } else {
        const bf16_t* arow = Wcat1 + (size_t)(w * HID + j0 + l) * LD1 + q * 8;
        const bf16_t* xA = h1buf + ((size_t)bA * T_SEQ + t) * HID + q * 8;
        const bf16_t* xB = h1buf + ((size_t)bB * T_SEQ + t) * HID + q * 8;
#pragma unroll 4
        for (int p = 0; p < 32; ++p) { // K panels from h1[t] (K=1024)
            bf16x8 a  = *(const bf16x8*)(arow + p * 32);
            bf16x8 b0 = *(const bf16x8*)(xA + p * 32);
            bf16x8 b1 = *(const bf16x8*)(xB + p * 32);
            acc0 = __builtin_amdgcn_mfma_f32_16x16x32_bf16(a, b0, acc0, 0, 0, 0);
            acc1 = __builtin_amdgcn_mfma_f32_16x16x32_bf16(a, b1, acc1, 0, 0, 0);
        }
        const bf16_t* hA = hr + (size_t)bA * HID + q * 8;
        const bf16_t* hB = hr + (size_t)bB * HID + q * 8;
#pragma unroll 4
        for (int p = 0; p < 32; ++p) { // K panels from recurrent h (K=1024)
            bf16x8 a  = *(const bf16x8*)(arow + HID + p * 32);
            bf16x8 b0 = *(const bf16x8*)(hA + p * 32);
            bf16x8 b1 = *(const bf16x8*)(hB + p * 32);
            acc0 = __builtin_amdgcn_mfma_f32_16x16x32_bf16(a, b0, acc0, 0, 0, 0);
            acc1 = __builtin_amdgcn_mfma_f32_16x16x32_bf16(a, b1, acc1, 0, 0, 0);
        }
    }

    // Epilogue: bias + activation, stage gates in LDS (D layout: row=q*4+r, col=lane&15)
#pragma unroll
    for (int r = 0; r < 4; ++r) {
        int row = q * 4 + r;
        float bv = bias[w * HID + j0 + row];
        float v0 = acc0[r] + bv;
        float v1 = acc1[r] + bv;
        if (w == 2) { v0 = tanh_f(v0); v1 = tanh_f(v1); }
        else        { v0 = sigm_f(v0); v1 = sigm_f(v1); }
        lds_g[w * 528 + row * 33 + l]      = v0;
        lds_g[w * 528 + row * 33 + 16 + l] = v1;
    }
    __syncthreads();

    // Elementwise LSTM cell update: 16 hidden x 32 batch per block
#pragma unroll
    for (int it = 0; it < 2; ++it) {
        int e = tid + it * 256;
        int j = e & 15;
        int n = e >> 4;
        int b = n0 + n;
        int jg = j0 + j;
        float iv = lds_g[   0 + j * 33 + n];
        float fv = lds_g[ 528 + j * 33 + n];
        float gv = lds_g[1056 + j * 33 + n];
        float ov = lds_g[1584 + j * 33 + n];
        size_t ci = (size_t)b * HID + jg;
        float cn = fv * cc[ci] + iv * gv;
        cc[ci] = cn;
        float hv = ov * tanh_f(cn);
        hw[ci] = (bf16_t)hv;
        if (layer == 0) {
            h1buf[((size_t)b * T_SEQ + t) * HID + jg] = (bf16_t)hv;
        } else {
            lds_h[j * 33 + n] = hv;
        }
    }

    // Fused FC (layer 1 only): partial K=16 dot per block, atomically accumulated
    if (layer == 1) {
        __syncthreads();
#pragma unroll
        for (int it = 0; it < 8; ++it) {
            int pe = tid + it * 256;
            int o = pe & 63;
            int n = pe >> 6;
            const float* wr = Wfc + (size_t)o * HID + j0;
            float s = 0.f;
#pragma unroll
            for (int j = 0; j < 16; ++j) s += wr[j] * lds_h[j * 33 + n];
            atomicAdd(&out[((size_t)(n0 + n) * T_SEQ + t) * 64 + o], s);
        }
    }
}

extern "C" void kernel_launch(void* const* d_in, const int* in_sizes, int n_in,
                              void* d_out, int out_size, void* d_ws, size_t ws_size,
                              hipStream_t stream)
{
    const float* x    = (const float*)d_in[0];
    const float* Wih0 = (const float*)d_in[1];
    const float* Whh0 = (const float*)d_in[2];
    const float* bih0 = (const float*)d_in[3];
    const float* bhh0 = (const float*)d_in[4];
    const float* Wih1 = (const float*)d_in[5];
    const float* Whh1 = (const float*)d_in[6];
    const float* bih1 = (const float*)d_in[7];
    const float* bhh1 = (const float*)d_in[8];
    const float* Wfc  = (const float*)d_in[9];
    const float* bfc  = (const float*)d_in[10];
    float* out = (float*)d_out;

    char* ws = (char*)d_ws;
    size_t off = 0;
    auto alloc = [&](size_t bytes) -> void* {
        void* p = ws + off;
        off += (bytes + 255) & ~(size_t)255;
        return p;
    };
    bf16_t* Wcat0 = (bf16_t*)alloc((size_t)4096 * LD0 * 2);       // 8.9 MB
    bf16_t* Wcat1 = (bf16_t*)alloc((size_t)4096 * LD1 * 2);       // 16.8 MB
    bf16_t* xbf   = (bf16_t*)alloc((size_t)NB * T_SEQ * FIN * 2); // 8.4 MB
    bf16_t* h1buf = (bf16_t*)alloc((size_t)NB * T_SEQ * HID * 2); // 134 MB
    bf16_t* hs0   = (bf16_t*)alloc((size_t)2 * HB * 2);           // double-buffered
    bf16_t* hs1   = (bf16_t*)alloc((size_t)2 * HB * 2);
    float*  c0    = (float*)alloc((size_t)HB * 4);
    float*  c1    = (float*)alloc((size_t)HB * 4);
    float*  bias0 = (float*)alloc(4096 * 4);
    float*  bias1 = (float*)alloc(4096 * 4);
    if (off > ws_size) return;  // ~170 MB needed; fail loudly via validation if短

    prep_kernel<<<1024, 256, 0, stream>>>(x, Wih0, Whh0, bih0, bhh0,
                                          Wih1, Whh1, bih1, bhh1, bfc,
                                          Wcat0, Wcat1, xbf, bias0, bias1,
                                          hs0, hs1, c0, c1, out);

    // Software-pipelined across layers: kernel k = L0 step k + L1 step k-1
    for (int k = 0; k <= T_SEQ; ++k) {
        lstm_step_kernel<<<512, 256, 0, stream>>>(k, Wcat0, bias0, xbf, hs0, c0, h1buf,
                                                  Wcat1, bias1, hs1, c1, Wfc, out);
    }
}